// Round 5
// baseline (259.676 us; speedup 1.0000x reference)
//
#include <hip/hip_runtime.h>
#include <hip/hip_bf16.h>
#include <cstdint>
#include <cstddef>
#include <math.h>

// Problem constants (reference: B=4096, D=256, T=0.5)
#define BSZ   4096
#define NROW  8192          // 2*B
#define DIM   256
#define INV_T 2.0f
#define EPS_N 1e-8f
#define CE    2.8853900817779268f   // INV_T * log2(e): e^(2x) = 2^(CE*x)
#define NTILE 2080                  // 64*65/2 upper-triangular 128-tiles

typedef __attribute__((ext_vector_type(8))) short bf16x8;   // 8 bf16 = 4 VGPRs
typedef __attribute__((ext_vector_type(4))) float f32x4;

__device__ __forceinline__ unsigned short f2bf(float x) {
    __hip_bfloat16 h = __float2bfloat16(x);
    return __builtin_bit_cast(unsigned short, h);
}
__device__ __forceinline__ float bf2f(unsigned short u) {
    __hip_bfloat16 h = __builtin_bit_cast(__hip_bfloat16, u);
    return __bfloat162float(h);
}

// async global->LDS 16B (wave-uniform LDS base + lane*16 layout)
__device__ __forceinline__ void load_lds16(const void* g, void* l) {
    __builtin_amdgcn_global_load_lds(
        (const __attribute__((address_space(1))) void*)g,
        (__attribute__((address_space(3))) void*)l,
        16, 0, 0);
}

// ---------------------------------------------------------------------------
// Kernel 1: row-normalize concat(z1,z2) -> bf16 zn; writes exact bf16 diag
// term sii[row]; zeroes rowsum and the gram completion counter.
__global__ __launch_bounds__(256)
void nt_normalize(const float* __restrict__ z1,
                  const float* __restrict__ z2,
                  __hip_bfloat16* __restrict__ zn,
                  float* __restrict__ rowsum,
                  float* __restrict__ sii,
                  int* __restrict__ cnt) {
    const int wave = threadIdx.x >> 6;
    const int lane = threadIdx.x & 63;
    const int row  = blockIdx.x * 4 + wave;
    const float* src = (row < BSZ) ? (z1 + (size_t)row * DIM)
                                   : (z2 + (size_t)(row - BSZ) * DIM);
    const float4 v = ((const float4*)src)[lane];
    float ss = v.x * v.x + v.y * v.y + v.z * v.z + v.w * v.w;
    #pragma unroll
    for (int off = 32; off; off >>= 1) ss += __shfl_xor(ss, off);
    const float rinv = 1.0f / fmaxf(sqrtf(ss), EPS_N);  // torch eps clamp
    ushort4 o;
    o.x = f2bf(v.x * rinv);
    o.y = f2bf(v.y * rinv);
    o.z = f2bf(v.z * rinv);
    o.w = f2bf(v.w * rinv);
    ((ushort4*)(zn + (size_t)row * DIM))[lane] = o;
    float bx = bf2f(o.x), by = bf2f(o.y), bz = bf2f(o.z), bw = bf2f(o.w);
    float s2 = bx * bx + by * by + bz * bz + bw * bw;
    #pragma unroll
    for (int off = 32; off; off >>= 1) s2 += __shfl_xor(s2, off);
    if (lane == 0) { sii[row] = s2; rowsum[row] = 0.0f; }
    if (blockIdx.x == 0 && threadIdx.x == 0) *cnt = 0;
}

// ---------------------------------------------------------------------------
// Kernel 2: Zn·Znᵀ upper triangle. BK=128 (2 K-iters, 4 barriers, 64 KB LDS,
// 2 blocks/CU). XOR-swizzled LDS (16 chunks/row, key=row&7) keeps reads
// 2-way/bank = free while global_load_lds keeps its identity lane layout.
// Last-finished block runs the loss reduction inline (device-scope handoff).
__global__ __launch_bounds__(256)
void nt_gram(const __hip_bfloat16* __restrict__ zn,
             float* __restrict__ rowsum,
             float* __restrict__ pos,
             const float* __restrict__ sii,
             int* __restrict__ cnt,
             float* __restrict__ out) {
    // Triangular decode: S(bi) = 64*bi - bi*(bi-1)/2 tiles before row bi.
    const int l = blockIdx.x;
    int bi = (int)((129.0 - sqrt(16641.0 - 8.0 * (double)l)) * 0.5);
    while (64 * (bi + 1) - (bi + 1) * bi / 2 <= l) ++bi;
    while (64 * bi - bi * (bi - 1) / 2 > l) --bi;
    const int bj = bi + (l - (64 * bi - bi * (bi - 1) / 2));

    __shared__ __hip_bfloat16 As[128 * 128];  // 32 KB, [128 rows][16 chunks x 16B]
    __shared__ __hip_bfloat16 Bs[128 * 128];  // 32 KB

    const int t    = threadIdx.x;
    const int lane = t & 63;
    const int wave = t >> 6;
    const int wrow = (wave >> 1) * 64;
    const int wcol = (wave & 1) * 64;
    const int q    = lane >> 4;
    const int r16  = lane & 15;
    const int sw   = r16 & 7;                 // read-side swizzle key

    f32x4 acc[4][4] = {};

    const __hip_bfloat16* Ag = zn + (size_t)bi * 128 * DIM;
    const __hip_bfloat16* Bg = zn + (size_t)bj * 128 * DIM;

    const int srow16 = t >> 4;                // 0..15
    const int gch    = (t & 15) ^ (srow16 & 7);   // swizzled global chunk (pass-inv)

    for (int k0 = 0; k0 < DIM; k0 += 128) {
        #pragma unroll
        for (int p = 0; p < 8; ++p) {
            const int row = p * 16 + srow16;
            load_lds16(Ag + (size_t)row * DIM + k0 + gch * 8,
                       (char*)As + p * 4096 + t * 16);
            load_lds16(Bg + (size_t)row * DIM + k0 + gch * 8,
                       (char*)Bs + p * 4096 + t * 16);
        }
        __syncthreads();

        #pragma unroll
        for (int kk = 0; kk < 128; kk += 32) {
            const int cc = (kk >> 3) + q;          // chunk index in row
            const int cpos = ((cc ^ sw) << 4);     // swizzled byte pos
            bf16x8 af[4], bfr[4];
            #pragma unroll
            for (int mi = 0; mi < 4; ++mi) {
                const int m = wrow + mi * 16 + r16;
                af[mi] = *(const bf16x8*)((const char*)As + m * 256 + cpos);
            }
            #pragma unroll
            for (int ni = 0; ni < 4; ++ni) {
                const int n = wcol + ni * 16 + r16;
                bfr[ni] = *(const bf16x8*)((const char*)Bs + n * 256 + cpos);
            }
            #pragma unroll
            for (int mi = 0; mi < 4; ++mi)
                #pragma unroll
                for (int ni = 0; ni < 4; ++ni)
                    acc[mi][ni] = __builtin_amdgcn_mfma_f32_16x16x32_bf16(
                        af[mi], bfr[ni], acc[mi][ni], 0, 0, 0);
        }
        __syncthreads();
    }

    // Epilogue. C/D layout: col=lane&15, row=(lane>>4)*4+reg (m89-verified).
    const int c = lane & 15;
    float colp[4] = {0.f, 0.f, 0.f, 0.f};

    #pragma unroll
    for (int mi = 0; mi < 4; ++mi) {
        #pragma unroll
        for (int r = 0; r < 4; ++r) {
            float s = 0.f;
            #pragma unroll
            for (int ni = 0; ni < 4; ++ni) {
                const float e = exp2f(acc[mi][ni][r] * CE);
                s += e;
                colp[ni] += e;
            }
            s += __shfl_xor(s, 1);
            s += __shfl_xor(s, 2);
            s += __shfl_xor(s, 4);
            s += __shfl_xor(s, 8);
            if (c == 0) {
                const int grow = bi * 128 + wrow + mi * 16 + q * 4 + r;
                atomicAdd(&rowsum[grow], s);
            }
        }
    }
    if (bi != bj) {       // column sums feed the bj strip by symmetry
        #pragma unroll
        for (int ni = 0; ni < 4; ++ni) {
            float cs = colp[ni];
            cs += __shfl_xor(cs, 16);
            cs += __shfl_xor(cs, 32);
            if (q == 0) atomicAdd(&rowsum[bj * 128 + wcol + ni * 16 + c], cs);
        }
    }
    // Positives: global diag offset +BSZ => bj==bi+32 strip, wrow==wcol waves.
    if (bj == bi + 32 && wrow == wcol) {
        #pragma unroll
        for (int mi = 0; mi < 4; ++mi)
            #pragma unroll
            for (int r = 0; r < 4; ++r)
                if (c == q * 4 + r) {
                    const int grow = bi * 128 + wrow + mi * 16 + q * 4 + r;
                    const float val = acc[mi][mi][r];
                    __hip_atomic_store(&pos[grow], val,
                                       __ATOMIC_RELAXED, __HIP_MEMORY_SCOPE_AGENT);
                    __hip_atomic_store(&pos[grow + BSZ], val,
                                       __ATOMIC_RELAXED, __HIP_MEMORY_SCOPE_AGENT);
                }
    }

    // ---- fused finalize: last block to arrive reduces the loss ----
    __threadfence();                      // release rowsum/pos device-wide
    __shared__ int is_last;
    if (t == 0) {
        int prev = __hip_atomic_fetch_add(cnt, 1, __ATOMIC_ACQ_REL,
                                          __HIP_MEMORY_SCOPE_AGENT);
        is_last = (prev == NTILE - 1);
    }
    __syncthreads();
    if (!is_last) return;
    __threadfence();                      // acquire

    float v = 0.f;
    for (int i = t; i < NROW; i += 256) {
        const float p  = __hip_atomic_load(&pos[i], __ATOMIC_RELAXED,
                                           __HIP_MEMORY_SCOPE_AGENT);
        const float rs = __hip_atomic_load(&rowsum[i], __ATOMIC_RELAXED,
                                           __HIP_MEMORY_SCOPE_AGENT);
        const float sv = __hip_atomic_load(&sii[i], __ATOMIC_RELAXED,
                                           __HIP_MEMORY_SCOPE_AGENT);
        const float pl  = p * INV_T;
        const float neg = rs - exp2f(sv * CE);     // drop diagonal term
        v += logf(__expf(pl) + neg) - pl;
    }
    #pragma unroll
    for (int off = 32; off; off >>= 1) v += __shfl_xor(v, off);
    __shared__ float red[4];
    if ((t & 63) == 0) red[t >> 6] = v;
    __syncthreads();
    if (t == 0) out[0] = (red[0] + red[1] + red[2] + red[3]) * (1.0f / NROW);
}

// ---------------------------------------------------------------------------
extern "C" void kernel_launch(void* const* d_in, const int* in_sizes, int n_in,
                              void* d_out, int out_size, void* d_ws, size_t ws_size,
                              hipStream_t stream) {
    const float* z1 = (const float*)d_in[0];
    const float* z2 = (const float*)d_in[1];
    float* out = (float*)d_out;

    __hip_bfloat16* zn = (__hip_bfloat16*)d_ws;                       // 4 MB
    float* rowsum = (float*)((char*)d_ws + (size_t)NROW * DIM * 2);   // 32 KB
    float* pos    = rowsum + NROW;                                    // 32 KB
    float* sii    = pos + NROW;                                       // 32 KB
    int*   cnt    = (int*)(sii + NROW);

    nt_normalize<<<NROW / 4, 256, 0, stream>>>(z1, z2, zn, rowsum, sii, cnt);
    nt_gram<<<NTILE, 256, 0, stream>>>(zn, rowsum, pos, sii, cnt, out);
}

// Round 6
// 107.047 us; speedup vs baseline: 2.4258x; 2.4258x over previous
//
#include <hip/hip_runtime.h>
#include <hip/hip_bf16.h>
#include <cstdint>
#include <cstddef>
#include <math.h>

// Problem constants (reference: B=4096, D=256, T=0.5)
#define BSZ   4096
#define NROW  8192          // 2*B
#define DIM   256
#define INV_T 2.0f
#define EPS_N 1e-8f
#define CE    2.8853900817779268f   // INV_T * log2(e): e^(2x) = 2^(CE*x)
#define NTILE 2080                  // 64*65/2 upper-triangular 128-tiles

typedef __attribute__((ext_vector_type(8))) short bf16x8;   // 8 bf16 = 4 VGPRs
typedef __attribute__((ext_vector_type(4))) float f32x4;

// ---------------------------------------------------------------------------
// Compile-time tile schedule for XCD L2 locality. blockIdx%8 == XCD (m09).
// Strips grouped 8x8 (64 KB/strip, 512 KB/group). Each XCD x gets:
//   - diagonal group-pair (x,x): 36 tiles
//   - 3 full off-diag pairs:    192 tiles
//   - half of a shared pair:     32 tiles          => 260 tiles/XCD, 2080 total
// Any ~96-slot resident window per XCD spans <=2.5 MB of strips < 4 MB L2.
struct TileOrder {
    unsigned short idx[NTILE];
    constexpr TileOrder() : idx{} {
        int pga[28] = {}, pgb[28] = {};
        int np = 0;
        for (int a = 0; a < 8; ++a)
            for (int b = a + 1; b < 8; ++b) { pga[np] = a; pgb[np] = b; ++np; }
        int seq[8][260] = {};
        for (int x = 0; x < 8; ++x) {
            int n = 0;
            for (int i = 0; i < 8; ++i)                  // diag pair (x,x)
                for (int j = i; j < 8; ++j)
                    seq[x][n++] = ((8 * x + i) << 8) | (8 * x + j);
            for (int p = 0; p < 3; ++p) {                // 3 full off-diag pairs
                const int ga = pga[3 * x + p], gb = pgb[3 * x + p];
                for (int i = 0; i < 8; ++i)
                    for (int j = 0; j < 8; ++j)
                        seq[x][n++] = ((8 * ga + i) << 8) | (8 * gb + j);
            }
            const int pi = 24 + x / 2;                   // shared half-pair
            const int ga = pga[pi], gb = pgb[pi];
            const int i0 = (x & 1) ? 4 : 0;
            for (int i = i0; i < i0 + 4; ++i)
                for (int j = 0; j < 8; ++j)
                    seq[x][n++] = ((8 * ga + i) << 8) | (8 * gb + j);
        }
        for (int l = 0; l < NTILE; ++l)
            idx[l] = (unsigned short)seq[l % 8][l / 8];
    }
};
__device__ constexpr TileOrder TO{};

__device__ __forceinline__ unsigned short f2bf(float x) {
    __hip_bfloat16 h = __float2bfloat16(x);
    return __builtin_bit_cast(unsigned short, h);
}
__device__ __forceinline__ float bf2f(unsigned short u) {
    __hip_bfloat16 h = __builtin_bit_cast(__hip_bfloat16, u);
    return __bfloat162float(h);
}

// async global->LDS 16B (wave-uniform LDS base + lane*16 layout)
__device__ __forceinline__ void load_lds16(const void* g, void* l) {
    __builtin_amdgcn_global_load_lds(
        (const __attribute__((address_space(1))) void*)g,
        (__attribute__((address_space(3))) void*)l,
        16, 0, 0);
}

// ---------------------------------------------------------------------------
// Kernel 1: row-normalize concat(z1,z2) -> bf16 zn; exact bf16 diag term
// sii[row] (finalize subtracts exp(2*sim_ii)); zeroes rowsum.
__global__ __launch_bounds__(256)
void nt_normalize(const float* __restrict__ z1,
                  const float* __restrict__ z2,
                  __hip_bfloat16* __restrict__ zn,
                  float* __restrict__ rowsum,
                  float* __restrict__ sii) {
    const int wave = threadIdx.x >> 6;
    const int lane = threadIdx.x & 63;
    const int row  = blockIdx.x * 4 + wave;
    const float* src = (row < BSZ) ? (z1 + (size_t)row * DIM)
                                   : (z2 + (size_t)(row - BSZ) * DIM);
    const float4 v = ((const float4*)src)[lane];
    float ss = v.x * v.x + v.y * v.y + v.z * v.z + v.w * v.w;
    #pragma unroll
    for (int off = 32; off; off >>= 1) ss += __shfl_xor(ss, off);
    const float rinv = 1.0f / fmaxf(sqrtf(ss), EPS_N);  // torch eps clamp
    ushort4 o;
    o.x = f2bf(v.x * rinv);
    o.y = f2bf(v.y * rinv);
    o.z = f2bf(v.z * rinv);
    o.w = f2bf(v.w * rinv);
    ((ushort4*)(zn + (size_t)row * DIM))[lane] = o;
    float bx = bf2f(o.x), by = bf2f(o.y), bz = bf2f(o.z), bw = bf2f(o.w);
    float s2 = bx * bx + by * by + bz * bz + bw * bw;
    #pragma unroll
    for (int off = 32; off; off >>= 1) s2 += __shfl_xor(s2, off);
    if (lane == 0) { sii[row] = s2; rowsum[row] = 0.0f; }
}

// ---------------------------------------------------------------------------
// Kernel 2: Zn·Znᵀ upper triangle. R3-proven core: BK=64, 32KB x2 LDS,
// XOR-swizzled (0 bank conflicts), global_load_lds width=16. Tile order from
// the constexpr XCD-locality schedule. Rowsum includes the diagonal
// (finalize subtracts); positives captured on the bj==bi+32 strip only.
__global__ __launch_bounds__(256)
void nt_gram(const __hip_bfloat16* __restrict__ zn,
             float* __restrict__ rowsum,
             float* __restrict__ pos) {
    const int code = TO.idx[blockIdx.x];
    const int bi = code >> 8, bj = code & 255;

    __shared__ __hip_bfloat16 As[128 * 64];  // 16 KB, [128 rows][8 chunks x 16B]
    __shared__ __hip_bfloat16 Bs[128 * 64];  // 16 KB

    const int t    = threadIdx.x;
    const int lane = t & 63;
    const int wave = t >> 6;
    const int wrow = (wave >> 1) * 64;
    const int wcol = (wave & 1) * 64;
    const int q    = lane >> 4;
    const int r16  = lane & 15;
    const int sw   = r16 & 7;                 // read-side swizzle key

    f32x4 acc[4][4] = {};

    const __hip_bfloat16* Ag = zn + (size_t)bi * 128 * DIM;
    const __hip_bfloat16* Bg = zn + (size_t)bj * 128 * DIM;

    const int srow = t >> 3;                  // 0..31 per pass
    const int sc   = (t & 7) ^ (srow & 7);    // swizzled global chunk (pass-inv)

    for (int k0 = 0; k0 < DIM; k0 += 64) {
        #pragma unroll
        for (int p = 0; p < 4; ++p) {
            const int row = p * 32 + srow;
            load_lds16(Ag + (size_t)row * DIM + k0 + sc * 8,
                       (char*)As + p * 4096 + t * 16);
            load_lds16(Bg + (size_t)row * DIM + k0 + sc * 8,
                       (char*)Bs + p * 4096 + t * 16);
        }
        __syncthreads();

        #pragma unroll
        for (int kk = 0; kk < 64; kk += 32) {
            const int cc = (kk >> 3) + q;          // chunk index in row
            const int cpos = (cc ^ sw) << 4;       // swizzled byte pos
            bf16x8 af[4], bfr[4];
            #pragma unroll
            for (int mi = 0; mi < 4; ++mi) {
                const int m = wrow + mi * 16 + r16;
                af[mi] = *(const bf16x8*)((const char*)As + m * 128 + cpos);
            }
            #pragma unroll
            for (int ni = 0; ni < 4; ++ni) {
                const int n = wcol + ni * 16 + r16;
                bfr[ni] = *(const bf16x8*)((const char*)Bs + n * 128 + cpos);
            }
            #pragma unroll
            for (int mi = 0; mi < 4; ++mi)
                #pragma unroll
                for (int ni = 0; ni < 4; ++ni)
                    acc[mi][ni] = __builtin_amdgcn_mfma_f32_16x16x32_bf16(
                        af[mi], bfr[ni], acc[mi][ni], 0, 0, 0);
        }
        __syncthreads();
    }

    // Epilogue. C/D layout: col=lane&15, row=(lane>>4)*4+reg (m89-verified).
    // Pure exp+accumulate; diagonal handled in finalize via sii.
    const int c = lane & 15;
    float colp[4] = {0.f, 0.f, 0.f, 0.f};

    #pragma unroll
    for (int mi = 0; mi < 4; ++mi) {
        #pragma unroll
        for (int r = 0; r < 4; ++r) {
            float s = 0.f;
            #pragma unroll
            for (int ni = 0; ni < 4; ++ni) {
                const float e = exp2f(acc[mi][ni][r] * CE);
                s += e;
                colp[ni] += e;
            }
            s += __shfl_xor(s, 1);
            s += __shfl_xor(s, 2);
            s += __shfl_xor(s, 4);
            s += __shfl_xor(s, 8);
            if (c == 0) {
                const int grow = bi * 128 + wrow + mi * 16 + q * 4 + r;
                atomicAdd(&rowsum[grow], s);
            }
        }
    }
    if (bi != bj) {       // column sums feed the bj strip by symmetry
        #pragma unroll
        for (int ni = 0; ni < 4; ++ni) {
            float cs = colp[ni];
            cs += __shfl_xor(cs, 16);
            cs += __shfl_xor(cs, 32);
            if (q == 0) atomicAdd(&rowsum[bj * 128 + wcol + ni * 16 + c], cs);
        }
    }
    // Positives: global diag offset +BSZ => bj==bi+32 strip, wrow==wcol waves.
    if (bj == bi + 32 && wrow == wcol) {
        #pragma unroll
        for (int mi = 0; mi < 4; ++mi)
            #pragma unroll
            for (int r = 0; r < 4; ++r)
                if (c == q * 4 + r) {
                    const int grow = bi * 128 + wrow + mi * 16 + q * 4 + r;
                    const float val = acc[mi][mi][r];
                    pos[grow] = val;
                    pos[grow + BSZ] = val;
                }
    }
}

// ---------------------------------------------------------------------------
// Kernel 3: single block; subtract diagonal, add positive, reduce, write out.
__global__ __launch_bounds__(1024)
void nt_finalize(const float* __restrict__ rowsum,
                 const float* __restrict__ pos,
                 const float* __restrict__ sii,
                 float* __restrict__ out) {
    float v = 0.f;
    for (int i = threadIdx.x; i < NROW; i += 1024) {
        const float pl  = pos[i] * INV_T;
        const float neg = rowsum[i] - exp2f(sii[i] * CE);  // drop diagonal
        v += logf(__expf(pl) + neg) - pl;
    }
    #pragma unroll
    for (int off = 32; off; off >>= 1) v += __shfl_xor(v, off);
    __shared__ float red[16];
    if ((threadIdx.x & 63) == 0) red[threadIdx.x >> 6] = v;
    __syncthreads();
    if (threadIdx.x == 0) {
        float s = 0.f;
        #pragma unroll
        for (int w = 0; w < 16; ++w) s += red[w];
        out[0] = s * (1.0f / NROW);
    }
}

// ---------------------------------------------------------------------------
extern "C" void kernel_launch(void* const* d_in, const int* in_sizes, int n_in,
                              void* d_out, int out_size, void* d_ws, size_t ws_size,
                              hipStream_t stream) {
    const float* z1 = (const float*)d_in[0];
    const float* z2 = (const float*)d_in[1];
    float* out = (float*)d_out;

    __hip_bfloat16* zn = (__hip_bfloat16*)d_ws;                       // 4 MB
    float* rowsum = (float*)((char*)d_ws + (size_t)NROW * DIM * 2);   // 32 KB
    float* pos    = rowsum + NROW;                                    // 32 KB (fully written by gram)
    float* sii    = pos + NROW;                                       // 32 KB

    nt_normalize<<<NROW / 4, 256, 0, stream>>>(z1, z2, zn, rowsum, sii);
    nt_gram<<<NTILE, 256, 0, stream>>>(zn, rowsum, pos);
    nt_finalize<<<1, 1024, 0, stream>>>(rowsum, pos, sii, out);
}